// Round 7
// baseline (295.628 us; speedup 1.0000x reference)
//
#include <hip/hip_runtime.h>
#include <stdint.h>

// ---------------------------------------------------------------------------
// SpatialGNN: 2x GATConv (2 heads -> 1 head), mean-pool per graph, MLP.
// R20: revert to R16 (265.6us verified; R17 perm / R18 4-lane / R19 LDS-fusion
//   all regressed -> agg structure is right, fusion/perm wrong). Single change:
//   agg1/agg2 edge loops unrolled 4 -> 8: doubles outstanding gathers per lane
//   against the ~500cy miss latency (R16 counters: 2.1 TB/s fill, VALU 42%,
//   occupancy ~30% -> latency-bound, not BW/VALU-bound).
//   7 dispatches, everything else identical to R16.
// ---------------------------------------------------------------------------

#define LRELU(x) ((x) > 0.f ? (x) : 0.2f * (x))
#define LOG2E 1.4426950408889634f
#define BCAP 3072  // slots per bucket; mean ~2230 at shift=7 (>19 sigma)
#define PSLICE 8   // pooled atomic slices

typedef short bf8 __attribute__((ext_vector_type(8)));   // 8 bf16 (4 VGPR)
typedef float f32x4 __attribute__((ext_vector_type(4))); // 4 fp32 acc
typedef float f32x2 __attribute__((ext_vector_type(2)));

__device__ __forceinline__ uint16_t f2bf(float f) {
  uint32_t u = __float_as_uint(f);
  u += 0x7fff + ((u >> 16) & 1);   // RNE
  return (uint16_t)(u >> 16);
}
__device__ __forceinline__ uint32_t pack2bf(float a, float b) {
  return (uint32_t)f2bf(a) | ((uint32_t)f2bf(b) << 16);
}
__device__ __forceinline__ uint8_t f2fp8(float v) {
  return (uint8_t)(__builtin_amdgcn_cvt_pk_fp8_f32(v, v, 0, false) & 0xff);
}
__device__ __forceinline__ void fp8x4_to_f32(uint32_t v, float* o) {
  f32x2 lo = __builtin_amdgcn_cvt_pk_f32_fp8(v, false);
  f32x2 hi = __builtin_amdgcn_cvt_pk_f32_fp8(v, true);
  o[0] = lo[0]; o[1] = lo[1]; o[2] = hi[0]; o[3] = hi[1];
}
__device__ __forceinline__ void a1_edge(const uint4& gv, float av, float* acc) {
  float f[16];
  fp8x4_to_f32(gv.x, f);     fp8x4_to_f32(gv.y, f + 4);
  fp8x4_to_f32(gv.z, f + 8); fp8x4_to_f32(gv.w, f + 12);
#pragma unroll
  for (int j = 0; j < 16; ++j) acc[j] = fmaf(av, f[j], acc[j]);
}
__device__ __forceinline__ void a2_edge(const uint2& gv, float av, float* acc) {
  float f[8];
  fp8x4_to_f32(gv.x, f); fp8x4_to_f32(gv.y, f + 4);
#pragma unroll
  for (int j = 0; j < 8; ++j) acc[j] = fmaf(av, f[j], acc[j]);
}

// ---------------- K1: edge scatter (fixed-stride buckets) + weight cvt -------
// record = (src << shift) | local_dst ; valid while N < 2^(32-shift).

__global__ __launch_bounds__(256) void scatter_cvt_kernel(
    const int* __restrict__ ei, int* __restrict__ bcur,
    uint32_t* __restrict__ bpack, const float* __restrict__ W1,
    const float* __restrict__ W2, uint16_t* __restrict__ WT1,
    uint16_t* __restrict__ WT2, int E, int E2, int shift, int nb, int gCH) {
  int blk = blockIdx.x;
  int t = threadIdx.x;
  if (blk >= gCH) {
    // ---- weight-convert tail blocks ----
    int idx = (blk - gCH) * 256 + t;
    if (idx < 128 * 128) {
      int n = idx >> 7, k = idx & 127;
      WT1[idx] = f2bf(W1[(size_t)k * 128 + n]);
    } else if (idx < 128 * 128 + 64 * 128) {
      int j = idx - 128 * 128;
      int n = j >> 7, k = j & 127;
      WT2[j] = f2bf(W2[(size_t)k * 64 + n]);
    }
    return;
  }
  __shared__ int lh[1024];
  __shared__ int lb[1024];
  for (int i = t; i < 1024; i += 256) lh[i] = 0;
  __syncthreads();
  int base = blk * 4096;
  int bszm1 = (1 << shift) - 1;
  uint32_t pk[16];
  int rk[16], bk[16];
#pragma unroll
  for (int u = 0; u < 16; ++u) {
    int e = base + u * 256 + t;
    if (e < E2) {
      int s, d;
      if (e < E) { s = ei[e]; d = ei[E + e]; } else { s = d = e - E; }
      bk[u] = d >> shift;
      pk[u] = ((uint32_t)s << shift) | (uint32_t)(d & bszm1);
      rk[u] = atomicAdd(&lh[bk[u]], 1);
    } else rk[u] = -1;
  }
  __syncthreads();
  for (int i = t; i < nb; i += 256) {
    int c = lh[i];
    lb[i] = c ? atomicAdd(&bcur[i], c) : 0;
  }
  __syncthreads();
#pragma unroll
  for (int u = 0; u < 16; ++u) {
    if (rk[u] >= 0) {
      int pos = lb[bk[u]] + rk[u];
      if (pos < BCAP) bpack[(size_t)bk[u] * BCAP + pos] = pk[u];
    }
  }
}

// ---------------- bucket finalize: hist, scan, rank-scatter ------------------

__device__ __forceinline__ void bfinal_body(const uint32_t* __restrict__ bpack,
                                            const int* __restrict__ bcur,
                                            int2* __restrict__ off2,
                                            int* __restrict__ ssrc, int N,
                                            int shift, int b) {
  __shared__ int hist[512];
  __shared__ int loff[512];
  __shared__ int ssc[256];
  __shared__ int lsrc[BCAP];
  int t = threadIdx.x;
  int bsz = 1 << shift;
  int node0 = b << shift;
  int e0 = b * BCAP;
  int cnt = min(bcur[b], BCAP);
  for (int i = t; i < bsz; i += 256) hist[i] = 0;
  __syncthreads();
  uint32_t pe[12];
  int ne = 0;
#pragma unroll
  for (int j = 0; j < 12; ++j) {
    int i = j * 256 + t;
    if (i < cnt) { pe[j] = bpack[(size_t)b * BCAP + i]; ne = j + 1; }
  }
  int bszm1 = bsz - 1;
  for (int j = 0; j < ne; ++j) atomicAdd(&hist[pe[j] & bszm1], 1);
  __syncthreads();
  int per = (bsz + 255) >> 8;                 // 1 or 2
  int basei = t * per;
  int va[2] = {0, 0};
  int sum = 0;
#pragma unroll 2
  for (int j = 0; j < per; ++j) {
    if (basei + j < bsz) va[j] = hist[basei + j];
    sum += va[j];
  }
  ssc[t] = sum;
  __syncthreads();
  for (int d = 1; d < 256; d <<= 1) {
    int x = (t >= d) ? ssc[t - d] : 0;
    __syncthreads();
    ssc[t] += x;
    __syncthreads();
  }
  int run = ssc[t] - sum;
#pragma unroll 2
  for (int j = 0; j < per; ++j) {
    if (basei + j < bsz) {
      loff[basei + j] = run;
      int v = node0 + basei + j;
      if (v < N) off2[v] = make_int2(e0 + run, e0 + run + va[j]);
      run += va[j];
    }
  }
  for (int i = t; i < bsz; i += 256) hist[i] = 0;
  __syncthreads();
  for (int j = 0; j < ne; ++j) {
    int ld = pe[j] & bszm1;
    int r = atomicAdd(&hist[ld], 1);
    lsrc[loff[ld] + r] = (int)(pe[j] >> shift);
  }
  __syncthreads();
  for (int i = t; i < cnt; i += 256) ssrc[e0 + i] = lsrc[i];  // coalesced
}

// ---------------- bf16 MFMA GEMM + fused escore; fp8 C output ----------------

template <int N, int HEADS, int AFP32>
__device__ __forceinline__ void gemm_body(const void* __restrict__ Av,
                                          const uint16_t* __restrict__ WT,
                                          uint8_t* __restrict__ C,
                                          const float* __restrict__ aS,
                                          const float* __restrict__ aD,
                                          float* __restrict__ es,
                                          float* __restrict__ ed, int M, int blk) {
  constexpr int CT = N / 16;           // col tiles
  int wave = threadIdx.x >> 6;
  int lane = threadIdx.x & 63;
  int m16 = lane & 15;
  int quad = lane >> 4;                // 0..3
  int row_base = blk * 128 + wave * 32;
  if (row_base >= M) return;           // M % 32 == 0 -> whole-wave guard exact
  const uint16_t* Ab0 = (const uint16_t*)Av + (size_t)(row_base + m16) * 128;
  const uint16_t* Ab1 = Ab0 + (size_t)16 * 128;
  const float* Af0 = (const float*)Av + (size_t)(row_base + m16) * 128;
  const float* Af1 = Af0 + (size_t)16 * 128;
  f32x4 acc[2][CT] = {};
#pragma unroll
  for (int ks = 0; ks < 4; ++ks) {
    int k0 = ks * 32 + quad * 8;
    bf8 a0, a1;
    if (AFP32) {
      float4 v0 = *reinterpret_cast<const float4*>(Af0 + k0);
      float4 v1 = *reinterpret_cast<const float4*>(Af0 + k0 + 4);
      uint4 pk0;
      pk0.x = pack2bf(v0.x, v0.y); pk0.y = pack2bf(v0.z, v0.w);
      pk0.z = pack2bf(v1.x, v1.y); pk0.w = pack2bf(v1.z, v1.w);
      a0 = *reinterpret_cast<bf8*>(&pk0);
      float4 w0 = *reinterpret_cast<const float4*>(Af1 + k0);
      float4 w1 = *reinterpret_cast<const float4*>(Af1 + k0 + 4);
      uint4 pk1;
      pk1.x = pack2bf(w0.x, w0.y); pk1.y = pack2bf(w0.z, w0.w);
      pk1.z = pack2bf(w1.x, w1.y); pk1.w = pack2bf(w1.z, w1.w);
      a1 = *reinterpret_cast<bf8*>(&pk1);
    } else {
      a0 = *reinterpret_cast<const bf8*>(Ab0 + k0);
      a1 = *reinterpret_cast<const bf8*>(Ab1 + k0);
    }
#pragma unroll
    for (int c = 0; c < CT; ++c) {
      bf8 b = *reinterpret_cast<const bf8*>(WT + (size_t)(c * 16 + m16) * 128 + k0);
      acc[0][c] = __builtin_amdgcn_mfma_f32_16x16x32_bf16(a0, b, acc[0][c], 0, 0, 0);
      acc[1][c] = __builtin_amdgcn_mfma_f32_16x16x32_bf16(a1, b, acc[1][c], 0, 0, 0);
    }
  }
  // C/D layout: col = lane&15, row = quad*4 + reg   [m89-verified]
#pragma unroll
  for (int r = 0; r < 2; ++r) {
#pragma unroll
    for (int c = 0; c < CT; ++c) {
#pragma unroll
      for (int reg = 0; reg < 4; ++reg) {
        int row = row_base + r * 16 + quad * 4 + reg;
        C[(size_t)row * N + c * 16 + m16] = f2fp8(acc[r][c][reg]);
      }
    }
  }
  // ---- fused escore epilogue (fp32 accumulators) ----
  float aSv[CT], aDv[CT];
#pragma unroll
  for (int c = 0; c < CT; ++c) {
    aSv[c] = aS[c * 16 + m16];
    aDv[c] = aD[c * 16 + m16];
  }
#pragma unroll
  for (int r = 0; r < 2; ++r) {
#pragma unroll
    for (int reg = 0; reg < 4; ++reg) {
      float es0 = 0.f, es1 = 0.f, ed0 = 0.f, ed1 = 0.f;
#pragma unroll
      for (int c = 0; c < CT; ++c) {
        float v = acc[r][c][reg];
        if (HEADS == 2 && c >= CT / 2) {
          es1 = fmaf(v, aSv[c], es1);
          ed1 = fmaf(v, aDv[c], ed1);
        } else {
          es0 = fmaf(v, aSv[c], es0);
          ed0 = fmaf(v, aDv[c], ed0);
        }
      }
#pragma unroll
      for (int o = 1; o < 16; o <<= 1) {
        es0 += __shfl_xor(es0, o);
        ed0 += __shfl_xor(ed0, o);
        if (HEADS == 2) {
          es1 += __shfl_xor(es1, o);
          ed1 += __shfl_xor(ed1, o);
        }
      }
      if (m16 == 0) {
        int row = row_base + r * 16 + quad * 4 + reg;
        if (HEADS == 2) {
          es[row * 2] = es0 * LOG2E; es[row * 2 + 1] = es1 * LOG2E;
          ed[row * 2] = ed0 * LOG2E; ed[row * 2 + 1] = ed1 * LOG2E;
        } else {
          es[row] = es0 * LOG2E;
          ed[row] = ed0 * LOG2E;
        }
      }
    }
  }
}

// ---- K2: layer-1 GEMM fused with bucket finalize (independent block ranges) -

__global__ __launch_bounds__(256) void gemm1_bfinal_kernel(
    const float* __restrict__ x, const uint16_t* __restrict__ WT1,
    uint8_t* __restrict__ hb1, const float* __restrict__ aS,
    const float* __restrict__ aD, float* __restrict__ es, float* __restrict__ ed,
    int M, const uint32_t* __restrict__ bpack, const int* __restrict__ bcur,
    int2* __restrict__ off2, int* __restrict__ ssrc, int shift, int gM) {
  int blk = blockIdx.x;
  if (blk < gM) {
    gemm_body<128, 2, 1>(x, WT1, hb1, aS, aD, es, ed, M, blk);
  } else {
    bfinal_body(bpack, bcur, off2, ssrc, M, shift, blk - gM);
  }
}

template <int N, int HEADS, int AFP32>
__global__ __launch_bounds__(256) void gemm_mfma(const void* __restrict__ Av,
                                                 const uint16_t* __restrict__ WT,
                                                 uint8_t* __restrict__ C,
                                                 const float* __restrict__ aS,
                                                 const float* __restrict__ aD,
                                                 float* __restrict__ es,
                                                 float* __restrict__ ed, int M) {
  gemm_body<N, HEADS, AFP32>(Av, WT, C, aS, aD, es, ed, M, blockIdx.x);
}

// ---------------- agg1: 8-lane group per node, uint4 fp8 gathers, unroll 8 ---
// grp = lane>>3 owns one node; cl = lane&7 covers channels cl*16..cl*16+15.

__global__ void agg1_kernel(const uint4* __restrict__ h16, const float* __restrict__ es,
                            const float2* __restrict__ ed, const int2* __restrict__ off2,
                            const int* __restrict__ ssrc, const float* __restrict__ b,
                            uint4* __restrict__ outb4, int n) {
  int wv = __builtin_amdgcn_readfirstlane((blockIdx.x * 256 + threadIdx.x) >> 6);
  int lane = threadIdx.x & 63;
  int grp = lane >> 3;         // node slot 0..7
  int cl = lane & 7;           // channel group: channels cl*16 .. cl*16+15
  int w = wv * 8 + grp;
  if (w >= n) return;
  bool hi = cl >= 4;           // head 1 channels (64..127)
  float2 edw = ed[w];
  float edh = hi ? edw.y : edw.x;          // pre-scaled by LOG2E
  const float* esp = es + (hi ? 1 : 0);    // head-offset pointer
  float acc[16] = {};
  float den = 0.f;
  int2 oo = off2[w];
  int e = oo.x, e1 = oo.y;
  for (; e + 8 <= e1; e += 8) {
    int s0 = ssrc[e];
    int s1 = ssrc[e + 1];
    int s2 = ssrc[e + 2];
    int s3 = ssrc[e + 3];
    int s4 = ssrc[e + 4];
    int s5 = ssrc[e + 5];
    int s6 = ssrc[e + 6];
    int s7 = ssrc[e + 7];
    uint4 g0 = h16[(size_t)s0 * 8 + cl];
    uint4 g1 = h16[(size_t)s1 * 8 + cl];
    uint4 g2 = h16[(size_t)s2 * 8 + cl];
    uint4 g3 = h16[(size_t)s3 * 8 + cl];
    uint4 g4 = h16[(size_t)s4 * 8 + cl];
    uint4 g5 = h16[(size_t)s5 * 8 + cl];
    uint4 g6 = h16[(size_t)s6 * 8 + cl];
    uint4 g7 = h16[(size_t)s7 * 8 + cl];
    float a0 = exp2f(LRELU(esp[2 * s0] + edh));
    float a1 = exp2f(LRELU(esp[2 * s1] + edh));
    float a2 = exp2f(LRELU(esp[2 * s2] + edh));
    float a3 = exp2f(LRELU(esp[2 * s3] + edh));
    float a4 = exp2f(LRELU(esp[2 * s4] + edh));
    float a5 = exp2f(LRELU(esp[2 * s5] + edh));
    float a6 = exp2f(LRELU(esp[2 * s6] + edh));
    float a7 = exp2f(LRELU(esp[2 * s7] + edh));
    den += ((a0 + a1) + (a2 + a3)) + ((a4 + a5) + (a6 + a7));
    a1_edge(g0, a0, acc);
    a1_edge(g1, a1, acc);
    a1_edge(g2, a2, acc);
    a1_edge(g3, a3, acc);
    a1_edge(g4, a4, acc);
    a1_edge(g5, a5, acc);
    a1_edge(g6, a6, acc);
    a1_edge(g7, a7, acc);
  }
  if (e + 4 <= e1) {
    int s0 = ssrc[e];
    int s1 = ssrc[e + 1];
    int s2 = ssrc[e + 2];
    int s3 = ssrc[e + 3];
    uint4 g0 = h16[(size_t)s0 * 8 + cl];
    uint4 g1 = h16[(size_t)s1 * 8 + cl];
    uint4 g2 = h16[(size_t)s2 * 8 + cl];
    uint4 g3 = h16[(size_t)s3 * 8 + cl];
    float a0 = exp2f(LRELU(esp[2 * s0] + edh));
    float a1 = exp2f(LRELU(esp[2 * s1] + edh));
    float a2 = exp2f(LRELU(esp[2 * s2] + edh));
    float a3 = exp2f(LRELU(esp[2 * s3] + edh));
    den += (a0 + a1) + (a2 + a3);
    a1_edge(g0, a0, acc);
    a1_edge(g1, a1, acc);
    a1_edge(g2, a2, acc);
    a1_edge(g3, a3, acc);
    e += 4;
  }
  for (; e < e1; ++e) {
    int s0 = ssrc[e];
    uint4 g0 = h16[(size_t)s0 * 8 + cl];
    float a0 = exp2f(LRELU(esp[2 * s0] + edh));
    den += a0;
    a1_edge(g0, a0, acc);
  }
  float inv = 1.0f / den;
  float o[16];
#pragma unroll
  for (int k = 0; k < 4; ++k) {
    float4 bb = reinterpret_cast<const float4*>(b)[cl * 4 + k];
    o[k * 4 + 0] = fmaxf(fmaf(acc[k * 4 + 0], inv, bb.x), 0.f);
    o[k * 4 + 1] = fmaxf(fmaf(acc[k * 4 + 1], inv, bb.y), 0.f);
    o[k * 4 + 2] = fmaxf(fmaf(acc[k * 4 + 2], inv, bb.z), 0.f);
    o[k * 4 + 3] = fmaxf(fmaf(acc[k * 4 + 3], inv, bb.w), 0.f);
  }
  uint4 oA, oB;
  oA.x = pack2bf(o[0], o[1]);   oA.y = pack2bf(o[2], o[3]);
  oA.z = pack2bf(o[4], o[5]);   oA.w = pack2bf(o[6], o[7]);
  oB.x = pack2bf(o[8], o[9]);   oB.y = pack2bf(o[10], o[11]);
  oB.z = pack2bf(o[12], o[13]); oB.w = pack2bf(o[14], o[15]);
  outb4[(size_t)w * 16 + cl * 2] = oA;      // bf16 row of 128 for GEMM2
  outb4[(size_t)w * 16 + cl * 2 + 1] = oB;
}

// ---- agg2+pool: 8-lane group per node, uint2 gathers, unroll 8 --------------

__global__ void agg2_pool_kernel(const uint2* __restrict__ h8,
                                 const float* __restrict__ es,
                                 const float* __restrict__ ed,
                                 const int2* __restrict__ off2,
                                 const int* __restrict__ ssrc,
                                 const float* __restrict__ b,
                                 const int* __restrict__ batch,
                                 float* __restrict__ pooled, int gstride, int n) {
  int t = threadIdx.x;
  int wv = __builtin_amdgcn_readfirstlane((blockIdx.x * 256 + t) >> 6);
  int wave = t >> 6;
  int lane = t & 63;
  int grp = lane >> 3;         // node slot 0..7
  int cl = lane & 7;           // channels cl*8 .. cl*8+7
  int w = wv * 8 + grp;
  bool act = (w < n);
  __shared__ float red[4][64];
  __shared__ int uniS[4];      // >=0 uniform graph; -1 empty; -2 handled
  float* pslice = pooled + (size_t)(blockIdx.x & (PSLICE - 1)) * gstride;
  float acc[8] = {};
  int g = -1;
  if (act) {
    g = batch[w];
    float edw = ed[w];         // pre-scaled by LOG2E
    float den = 0.f;
    int2 oo = off2[w];
    int e = oo.x, e1 = oo.y;
    for (; e + 8 <= e1; e += 8) {
      int s0 = ssrc[e];
      int s1 = ssrc[e + 1];
      int s2 = ssrc[e + 2];
      int s3 = ssrc[e + 3];
      int s4 = ssrc[e + 4];
      int s5 = ssrc[e + 5];
      int s6 = ssrc[e + 6];
      int s7 = ssrc[e + 7];
      uint2 g0 = h8[(size_t)s0 * 8 + cl];
      uint2 g1 = h8[(size_t)s1 * 8 + cl];
      uint2 g2 = h8[(size_t)s2 * 8 + cl];
      uint2 g3 = h8[(size_t)s3 * 8 + cl];
      uint2 g4 = h8[(size_t)s4 * 8 + cl];
      uint2 g5 = h8[(size_t)s5 * 8 + cl];
      uint2 g6 = h8[(size_t)s6 * 8 + cl];
      uint2 g7 = h8[(size_t)s7 * 8 + cl];
      float a0 = exp2f(LRELU(es[s0] + edw));
      float a1 = exp2f(LRELU(es[s1] + edw));
      float a2 = exp2f(LRELU(es[s2] + edw));
      float a3 = exp2f(LRELU(es[s3] + edw));
      float a4 = exp2f(LRELU(es[s4] + edw));
      float a5 = exp2f(LRELU(es[s5] + edw));
      float a6 = exp2f(LRELU(es[s6] + edw));
      float a7 = exp2f(LRELU(es[s7] + edw));
      den += ((a0 + a1) + (a2 + a3)) + ((a4 + a5) + (a6 + a7));
      a2_edge(g0, a0, acc);
      a2_edge(g1, a1, acc);
      a2_edge(g2, a2, acc);
      a2_edge(g3, a3, acc);
      a2_edge(g4, a4, acc);
      a2_edge(g5, a5, acc);
      a2_edge(g6, a6, acc);
      a2_edge(g7, a7, acc);
    }
    if (e + 4 <= e1) {
      int s0 = ssrc[e];
      int s1 = ssrc[e + 1];
      int s2 = ssrc[e + 2];
      int s3 = ssrc[e + 3];
      uint2 g0 = h8[(size_t)s0 * 8 + cl];
      uint2 g1 = h8[(size_t)s1 * 8 + cl];
      uint2 g2 = h8[(size_t)s2 * 8 + cl];
      uint2 g3 = h8[(size_t)s3 * 8 + cl];
      float a0 = exp2f(LRELU(es[s0] + edw));
      float a1 = exp2f(LRELU(es[s1] + edw));
      float a2 = exp2f(LRELU(es[s2] + edw));
      float a3 = exp2f(LRELU(es[s3] + edw));
      den += (a0 + a1) + (a2 + a3);
      a2_edge(g0, a0, acc);
      a2_edge(g1, a1, acc);
      a2_edge(g2, a2, acc);
      a2_edge(g3, a3, acc);
      e += 4;
    }
    for (; e < e1; ++e) {
      int s0 = ssrc[e];
      uint2 g0 = h8[(size_t)s0 * 8 + cl];
      float a0 = exp2f(LRELU(es[s0] + edw));
      den += a0;
      a2_edge(g0, a0, acc);
    }
    float inv = 1.0f / den;
    float4 b0 = reinterpret_cast<const float4*>(b)[cl * 2];
    float4 b1 = reinterpret_cast<const float4*>(b)[cl * 2 + 1];
    acc[0] = fmaf(acc[0], inv, b0.x);
    acc[1] = fmaf(acc[1], inv, b0.y);
    acc[2] = fmaf(acc[2], inv, b0.z);
    acc[3] = fmaf(acc[3], inv, b0.w);
    acc[4] = fmaf(acc[4], inv, b1.x);
    acc[5] = fmaf(acc[5], inv, b1.y);
    acc[6] = fmaf(acc[6], inv, b1.z);
    acc[7] = fmaf(acc[7], inv, b1.w);
  }
  // wave-level uniformity over the 8 nodes
  int g0lane = __shfl(g, 0);
  bool same = __all(g == g0lane);
  if (same && g0lane >= 0) {
    // butterfly over grp axis (lane bits 3,4,5)
#pragma unroll
    for (int m = 8; m <= 32; m <<= 1) {
#pragma unroll
      for (int j = 0; j < 8; ++j) acc[j] += __shfl_xor(acc[j], m);
    }
    if (grp == 0) {
#pragma unroll
      for (int j = 0; j < 8; ++j) red[wave][cl * 8 + j] = acc[j];
    }
    if (lane == 0) uniS[wave] = g0lane;
  } else {
    if (lane == 0) uniS[wave] = same ? -1 : -2;
    if (act && !same) {
      // rare mixed wave: per-node scalar atomics
#pragma unroll
      for (int j = 0; j < 8; ++j)
        atomicAdd(&pslice[(size_t)g * 64 + cl * 8 + j], acc[j]);
    }
  }
  __syncthreads();
  int u0 = uniS[0];
  bool allsame = (u0 >= 0) & (uniS[1] == u0) & (uniS[2] == u0) & (uniS[3] == u0);
  if (allsame) {
    if (t < 64) {
      float s = red[0][t] + red[1][t] + red[2][t] + red[3][t];
      atomicAdd(&pslice[(size_t)u0 * 64 + t], s);
    }
  } else {
    int gw = uniS[wave];
    if (gw >= 0) atomicAdd(&pslice[(size_t)gw * 64 + lane], red[wave][lane]);
  }
}

// ---------------- fused decoder MLP (counts via binary search) ---------------

__device__ __forceinline__ int lowerb(const int* __restrict__ a, int n, int v) {
  int lo = 0, hi = n;
  while (lo < hi) {
    int mid = (lo + hi) >> 1;
    if (a[mid] < v) lo = mid + 1; else hi = mid;
  }
  return lo;
}

__global__ void mlp_kernel(const float* __restrict__ pooled, int gstride,
                           const int* __restrict__ batch, int n,
                           const float* __restrict__ dw1, const float* __restrict__ db1,
                           const float* __restrict__ dw2, const float* __restrict__ db2,
                           float* __restrict__ out) {
  int g = blockIdx.x;
  int c = threadIdx.x;  // 64
  __shared__ float P[64];
  __shared__ float Z[64];
  __shared__ int cntS;
  if (c == 0) cntS = lowerb(batch, n, g + 1) - lowerb(batch, n, g);
  __syncthreads();
  float inv = 1.0f / fmaxf((float)cntS, 1.0f);
  float p = 0.f;
#pragma unroll
  for (int s = 0; s < PSLICE; ++s) p += pooled[(size_t)s * gstride + g * 64 + c];
  P[c] = p * inv;
  __syncthreads();
  float s = db1[c];
#pragma unroll
  for (int k = 0; k < 64; ++k) s = fmaf(P[k], dw1[k * 64 + c], s);
  Z[c] = fmaxf(s, 0.f);
  __syncthreads();
  if (c < 16) {
    float s2 = db2[c];
#pragma unroll
    for (int c2 = 0; c2 < 64; ++c2) s2 = fmaf(Z[c2], dw2[c2 * 16 + c], s2);
    out[g * 16 + c] = s2;
  }
}

// ---------------- launch ----------------

extern "C" void kernel_launch(void* const* d_in, const int* in_sizes, int n_in,
                              void* d_out, int out_size, void* d_ws, size_t ws_size,
                              hipStream_t stream) {
  const float* x      = (const float*)d_in[0];
  const int*   ei     = (const int*)d_in[1];
  const int*   batch  = (const int*)d_in[2];
  const float* W1     = (const float*)d_in[3];
  const float* a_src1 = (const float*)d_in[4];
  const float* a_dst1 = (const float*)d_in[5];
  const float* b1     = (const float*)d_in[6];
  const float* W2     = (const float*)d_in[7];
  const float* a_src2 = (const float*)d_in[8];
  const float* a_dst2 = (const float*)d_in[9];
  const float* b2     = (const float*)d_in[10];
  const float* dw1    = (const float*)d_in[11];
  const float* db1    = (const float*)d_in[12];
  const float* dw2    = (const float*)d_in[13];
  const float* db2    = (const float*)d_in[14];
  float* out = (float*)d_out;

  const int N = in_sizes[2];
  const int E = in_sizes[1] / 2;
  const int E2 = E + N;
  const int G = out_size / 16;
  const int gstride = G * 64;

  // bucket = 1<<shift nodes; need NB <= 1024 and bsz <= 512
  int shift = 7;
  while ((N >> shift) >= 1024) ++shift;
  const int NB = ((N - 1) >> shift) + 1;

  char* ws = (char*)d_ws;
  size_t o = 0;
  auto alloc = [&](size_t bytes) {
    void* p = ws + o;
    o = (o + bytes + 255) & ~(size_t)255;
    return p;
  };
  // zero region: bcur | pooled slices  (single memset)
  int*      zreg   = (int*)alloc((size_t)(1024 + PSLICE * gstride) * 4);
  int*      bcur   = zreg;
  float*    pooled = (float*)(zreg + 1024);
  int2*     off2   = (int2*)alloc((size_t)N * 8);
  uint32_t* bpack  = (uint32_t*)alloc((size_t)NB * BCAP * 4);
  int*      ssrc   = (int*)alloc((size_t)NB * BCAP * 4);
  float*    es1    = (float*)alloc((size_t)N * 2 * 4);
  float*    ed1    = (float*)alloc((size_t)N * 2 * 4);
  float*    es2    = (float*)alloc((size_t)N * 4);
  float*    ed2    = (float*)alloc((size_t)N * 4);
  uint16_t* wt1b   = (uint16_t*)alloc((size_t)128 * 128 * 2);
  uint16_t* wt2b   = (uint16_t*)alloc((size_t)64 * 128 * 2);
  uint8_t*  hb1    = (uint8_t*)alloc((size_t)N * 128);       // fp8 h1
  uint8_t*  hb2    = (uint8_t*)alloc((size_t)N * 64);        // fp8 h2
  uint32_t* out1b  = (uint32_t*)alloc((size_t)N * 64 * 4);   // bf16 out1 (packed)

  hipMemsetAsync(zreg, 0, (size_t)(1024 + PSLICE * gstride) * 4, stream);

  int gM   = (N + 127) / 128;             // mfma gemm blocks (128 rows each)
  int gW   = (N + 31) / 32;               // agg blocks (32 nodes each)
  int gCH  = (E2 + 4095) / 4096;          // scatter blocks
  int gCVT = (128 * 128 + 64 * 128 + 255) / 256;  // weight-cvt tail blocks

  // K1: edge scatter into fixed-stride buckets + weight convert
  scatter_cvt_kernel<<<gCH + gCVT, 256, 0, stream>>>(ei, bcur, bpack, W1, W2,
                                                     wt1b, wt2b, E, E2, shift,
                                                     NB, gCH);
  // K2: layer-1 GEMM (fp32 A, fused x-convert, fused escore) + bucket finalize
  gemm1_bfinal_kernel<<<gM + NB, 256, 0, stream>>>(x, wt1b, hb1, a_src1, a_dst1,
                                                   es1, ed1, N, bpack, bcur,
                                                   off2, ssrc, shift, gM);
  // K3: layer-1 aggregation (8-lane groups, uint4 gathers, unroll 8)
  agg1_kernel<<<gW, 256, 0, stream>>>((const uint4*)hb1, es1,
                                      (const float2*)ed1, off2, ssrc, b1,
                                      (uint4*)out1b, N);
  // K4: layer-2 GEMM (bf16 A) + fused escore
  gemm_mfma<64, 1, 0><<<gM, 256, 0, stream>>>((const void*)out1b, wt2b, hb2,
                                              a_src2, a_dst2, es2, ed2, N);
  // K5: layer-2 aggregation fused with pooled accumulation (unroll 8)
  agg2_pool_kernel<<<gW, 256, 0, stream>>>((const uint2*)hb2, es2, ed2, off2,
                                           ssrc, b2, batch, pooled, gstride, N);
  // K6: decoder MLP (per-graph counts via binary search on sorted batch)
  mlp_kernel<<<G, 64, 0, stream>>>(pooled, gstride, batch, N, dw1, db1, dw2,
                                   db2, out);
}

// Round 8
// 263.465 us; speedup vs baseline: 1.1221x; 1.1221x over previous
//
#include <hip/hip_runtime.h>
#include <stdint.h>

// ---------------------------------------------------------------------------
// SpatialGNN: 2x GATConv (2 heads -> 1 head), mean-pool per graph, MLP.
// R21: exact revert to R16 (265.6us verified best). Departures all regressed,
//   each counter-diagnosed: R17 perm (scattered per-node access), R18 4-lane
//   (neutral reshape), R19 LDS-fusion (occupancy kill), R20 unroll-8 (VGPR
//   spill: WRITE 25->100MB scratch traffic). agg kernels sit at the 8xXCD
//   L2-replication fetch floor (~95/65MB) at ~2.2-2.7 TB/s random-gather
//   fill -- five mechanisms to move them falsified. This is the floor.
//   7 dispatches: memset, scatter+cvt, gemm1+bfinal, agg1, gemm2, agg2+pool,
//   mlp.
// ---------------------------------------------------------------------------

#define LRELU(x) ((x) > 0.f ? (x) : 0.2f * (x))
#define LOG2E 1.4426950408889634f
#define BCAP 3072  // slots per bucket; mean ~2230 at shift=7 (>19 sigma)
#define PSLICE 8   // pooled atomic slices

typedef short bf8 __attribute__((ext_vector_type(8)));   // 8 bf16 (4 VGPR)
typedef float f32x4 __attribute__((ext_vector_type(4))); // 4 fp32 acc
typedef float f32x2 __attribute__((ext_vector_type(2)));

__device__ __forceinline__ uint16_t f2bf(float f) {
  uint32_t u = __float_as_uint(f);
  u += 0x7fff + ((u >> 16) & 1);   // RNE
  return (uint16_t)(u >> 16);
}
__device__ __forceinline__ uint32_t pack2bf(float a, float b) {
  return (uint32_t)f2bf(a) | ((uint32_t)f2bf(b) << 16);
}
__device__ __forceinline__ uint8_t f2fp8(float v) {
  return (uint8_t)(__builtin_amdgcn_cvt_pk_fp8_f32(v, v, 0, false) & 0xff);
}
__device__ __forceinline__ void fp8x4_to_f32(uint32_t v, float* o) {
  f32x2 lo = __builtin_amdgcn_cvt_pk_f32_fp8(v, false);
  f32x2 hi = __builtin_amdgcn_cvt_pk_f32_fp8(v, true);
  o[0] = lo[0]; o[1] = lo[1]; o[2] = hi[0]; o[3] = hi[1];
}
__device__ __forceinline__ void a1_edge(const uint4& gv, float av, float* acc) {
  float f[16];
  fp8x4_to_f32(gv.x, f);     fp8x4_to_f32(gv.y, f + 4);
  fp8x4_to_f32(gv.z, f + 8); fp8x4_to_f32(gv.w, f + 12);
#pragma unroll
  for (int j = 0; j < 16; ++j) acc[j] = fmaf(av, f[j], acc[j]);
}
__device__ __forceinline__ void a2_edge(const uint2& gv, float av, float* acc) {
  float f[8];
  fp8x4_to_f32(gv.x, f); fp8x4_to_f32(gv.y, f + 4);
#pragma unroll
  for (int j = 0; j < 8; ++j) acc[j] = fmaf(av, f[j], acc[j]);
}

// ---------------- K1: edge scatter (fixed-stride buckets) + weight cvt -------
// record = (src << shift) | local_dst ; valid while N < 2^(32-shift).

__global__ __launch_bounds__(256) void scatter_cvt_kernel(
    const int* __restrict__ ei, int* __restrict__ bcur,
    uint32_t* __restrict__ bpack, const float* __restrict__ W1,
    const float* __restrict__ W2, uint16_t* __restrict__ WT1,
    uint16_t* __restrict__ WT2, int E, int E2, int shift, int nb, int gCH) {
  int blk = blockIdx.x;
  int t = threadIdx.x;
  if (blk >= gCH) {
    // ---- weight-convert tail blocks ----
    int idx = (blk - gCH) * 256 + t;
    if (idx < 128 * 128) {
      int n = idx >> 7, k = idx & 127;
      WT1[idx] = f2bf(W1[(size_t)k * 128 + n]);
    } else if (idx < 128 * 128 + 64 * 128) {
      int j = idx - 128 * 128;
      int n = j >> 7, k = j & 127;
      WT2[j] = f2bf(W2[(size_t)k * 64 + n]);
    }
    return;
  }
  __shared__ int lh[1024];
  __shared__ int lb[1024];
  for (int i = t; i < 1024; i += 256) lh[i] = 0;
  __syncthreads();
  int base = blk * 4096;
  int bszm1 = (1 << shift) - 1;
  uint32_t pk[16];
  int rk[16], bk[16];
#pragma unroll
  for (int u = 0; u < 16; ++u) {
    int e = base + u * 256 + t;
    if (e < E2) {
      int s, d;
      if (e < E) { s = ei[e]; d = ei[E + e]; } else { s = d = e - E; }
      bk[u] = d >> shift;
      pk[u] = ((uint32_t)s << shift) | (uint32_t)(d & bszm1);
      rk[u] = atomicAdd(&lh[bk[u]], 1);
    } else rk[u] = -1;
  }
  __syncthreads();
  for (int i = t; i < nb; i += 256) {
    int c = lh[i];
    lb[i] = c ? atomicAdd(&bcur[i], c) : 0;
  }
  __syncthreads();
#pragma unroll
  for (int u = 0; u < 16; ++u) {
    if (rk[u] >= 0) {
      int pos = lb[bk[u]] + rk[u];
      if (pos < BCAP) bpack[(size_t)bk[u] * BCAP + pos] = pk[u];
    }
  }
}

// ---------------- bucket finalize: hist, scan, rank-scatter ------------------

__device__ __forceinline__ void bfinal_body(const uint32_t* __restrict__ bpack,
                                            const int* __restrict__ bcur,
                                            int2* __restrict__ off2,
                                            int* __restrict__ ssrc, int N,
                                            int shift, int b) {
  __shared__ int hist[512];
  __shared__ int loff[512];
  __shared__ int ssc[256];
  __shared__ int lsrc[BCAP];
  int t = threadIdx.x;
  int bsz = 1 << shift;
  int node0 = b << shift;
  int e0 = b * BCAP;
  int cnt = min(bcur[b], BCAP);
  for (int i = t; i < bsz; i += 256) hist[i] = 0;
  __syncthreads();
  uint32_t pe[12];
  int ne = 0;
#pragma unroll
  for (int j = 0; j < 12; ++j) {
    int i = j * 256 + t;
    if (i < cnt) { pe[j] = bpack[(size_t)b * BCAP + i]; ne = j + 1; }
  }
  int bszm1 = bsz - 1;
  for (int j = 0; j < ne; ++j) atomicAdd(&hist[pe[j] & bszm1], 1);
  __syncthreads();
  int per = (bsz + 255) >> 8;                 // 1 or 2
  int basei = t * per;
  int va[2] = {0, 0};
  int sum = 0;
#pragma unroll 2
  for (int j = 0; j < per; ++j) {
    if (basei + j < bsz) va[j] = hist[basei + j];
    sum += va[j];
  }
  ssc[t] = sum;
  __syncthreads();
  for (int d = 1; d < 256; d <<= 1) {
    int x = (t >= d) ? ssc[t - d] : 0;
    __syncthreads();
    ssc[t] += x;
    __syncthreads();
  }
  int run = ssc[t] - sum;
#pragma unroll 2
  for (int j = 0; j < per; ++j) {
    if (basei + j < bsz) {
      loff[basei + j] = run;
      int v = node0 + basei + j;
      if (v < N) off2[v] = make_int2(e0 + run, e0 + run + va[j]);
      run += va[j];
    }
  }
  for (int i = t; i < bsz; i += 256) hist[i] = 0;
  __syncthreads();
  for (int j = 0; j < ne; ++j) {
    int ld = pe[j] & bszm1;
    int r = atomicAdd(&hist[ld], 1);
    lsrc[loff[ld] + r] = (int)(pe[j] >> shift);
  }
  __syncthreads();
  for (int i = t; i < cnt; i += 256) ssrc[e0 + i] = lsrc[i];  // coalesced
}

// ---------------- bf16 MFMA GEMM + fused escore; fp8 C output ----------------

template <int N, int HEADS, int AFP32>
__device__ __forceinline__ void gemm_body(const void* __restrict__ Av,
                                          const uint16_t* __restrict__ WT,
                                          uint8_t* __restrict__ C,
                                          const float* __restrict__ aS,
                                          const float* __restrict__ aD,
                                          float* __restrict__ es,
                                          float* __restrict__ ed, int M, int blk) {
  constexpr int CT = N / 16;           // col tiles
  int wave = threadIdx.x >> 6;
  int lane = threadIdx.x & 63;
  int m16 = lane & 15;
  int quad = lane >> 4;                // 0..3
  int row_base = blk * 128 + wave * 32;
  if (row_base >= M) return;           // M % 32 == 0 -> whole-wave guard exact
  const uint16_t* Ab0 = (const uint16_t*)Av + (size_t)(row_base + m16) * 128;
  const uint16_t* Ab1 = Ab0 + (size_t)16 * 128;
  const float* Af0 = (const float*)Av + (size_t)(row_base + m16) * 128;
  const float* Af1 = Af0 + (size_t)16 * 128;
  f32x4 acc[2][CT] = {};
#pragma unroll
  for (int ks = 0; ks < 4; ++ks) {
    int k0 = ks * 32 + quad * 8;
    bf8 a0, a1;
    if (AFP32) {
      float4 v0 = *reinterpret_cast<const float4*>(Af0 + k0);
      float4 v1 = *reinterpret_cast<const float4*>(Af0 + k0 + 4);
      uint4 pk0;
      pk0.x = pack2bf(v0.x, v0.y); pk0.y = pack2bf(v0.z, v0.w);
      pk0.z = pack2bf(v1.x, v1.y); pk0.w = pack2bf(v1.z, v1.w);
      a0 = *reinterpret_cast<bf8*>(&pk0);
      float4 w0 = *reinterpret_cast<const float4*>(Af1 + k0);
      float4 w1 = *reinterpret_cast<const float4*>(Af1 + k0 + 4);
      uint4 pk1;
      pk1.x = pack2bf(w0.x, w0.y); pk1.y = pack2bf(w0.z, w0.w);
      pk1.z = pack2bf(w1.x, w1.y); pk1.w = pack2bf(w1.z, w1.w);
      a1 = *reinterpret_cast<bf8*>(&pk1);
    } else {
      a0 = *reinterpret_cast<const bf8*>(Ab0 + k0);
      a1 = *reinterpret_cast<const bf8*>(Ab1 + k0);
    }
#pragma unroll
    for (int c = 0; c < CT; ++c) {
      bf8 b = *reinterpret_cast<const bf8*>(WT + (size_t)(c * 16 + m16) * 128 + k0);
      acc[0][c] = __builtin_amdgcn_mfma_f32_16x16x32_bf16(a0, b, acc[0][c], 0, 0, 0);
      acc[1][c] = __builtin_amdgcn_mfma_f32_16x16x32_bf16(a1, b, acc[1][c], 0, 0, 0);
    }
  }
  // C/D layout: col = lane&15, row = quad*4 + reg   [m89-verified]
#pragma unroll
  for (int r = 0; r < 2; ++r) {
#pragma unroll
    for (int c = 0; c < CT; ++c) {
#pragma unroll
      for (int reg = 0; reg < 4; ++reg) {
        int row = row_base + r * 16 + quad * 4 + reg;
        C[(size_t)row * N + c * 16 + m16] = f2fp8(acc[r][c][reg]);
      }
    }
  }
  // ---- fused escore epilogue (fp32 accumulators) ----
  float aSv[CT], aDv[CT];
#pragma unroll
  for (int c = 0; c < CT; ++c) {
    aSv[c] = aS[c * 16 + m16];
    aDv[c] = aD[c * 16 + m16];
  }
#pragma unroll
  for (int r = 0; r < 2; ++r) {
#pragma unroll
    for (int reg = 0; reg < 4; ++reg) {
      float es0 = 0.f, es1 = 0.f, ed0 = 0.f, ed1 = 0.f;
#pragma unroll
      for (int c = 0; c < CT; ++c) {
        float v = acc[r][c][reg];
        if (HEADS == 2 && c >= CT / 2) {
          es1 = fmaf(v, aSv[c], es1);
          ed1 = fmaf(v, aDv[c], ed1);
        } else {
          es0 = fmaf(v, aSv[c], es0);
          ed0 = fmaf(v, aDv[c], ed0);
        }
      }
#pragma unroll
      for (int o = 1; o < 16; o <<= 1) {
        es0 += __shfl_xor(es0, o);
        ed0 += __shfl_xor(ed0, o);
        if (HEADS == 2) {
          es1 += __shfl_xor(es1, o);
          ed1 += __shfl_xor(ed1, o);
        }
      }
      if (m16 == 0) {
        int row = row_base + r * 16 + quad * 4 + reg;
        if (HEADS == 2) {
          es[row * 2] = es0 * LOG2E; es[row * 2 + 1] = es1 * LOG2E;
          ed[row * 2] = ed0 * LOG2E; ed[row * 2 + 1] = ed1 * LOG2E;
        } else {
          es[row] = es0 * LOG2E;
          ed[row] = ed0 * LOG2E;
        }
      }
    }
  }
}

// ---- K2: layer-1 GEMM fused with bucket finalize (independent block ranges) -

__global__ __launch_bounds__(256) void gemm1_bfinal_kernel(
    const float* __restrict__ x, const uint16_t* __restrict__ WT1,
    uint8_t* __restrict__ hb1, const float* __restrict__ aS,
    const float* __restrict__ aD, float* __restrict__ es, float* __restrict__ ed,
    int M, const uint32_t* __restrict__ bpack, const int* __restrict__ bcur,
    int2* __restrict__ off2, int* __restrict__ ssrc, int shift, int gM) {
  int blk = blockIdx.x;
  if (blk < gM) {
    gemm_body<128, 2, 1>(x, WT1, hb1, aS, aD, es, ed, M, blk);
  } else {
    bfinal_body(bpack, bcur, off2, ssrc, M, shift, blk - gM);
  }
}

template <int N, int HEADS, int AFP32>
__global__ __launch_bounds__(256) void gemm_mfma(const void* __restrict__ Av,
                                                 const uint16_t* __restrict__ WT,
                                                 uint8_t* __restrict__ C,
                                                 const float* __restrict__ aS,
                                                 const float* __restrict__ aD,
                                                 float* __restrict__ es,
                                                 float* __restrict__ ed, int M) {
  gemm_body<N, HEADS, AFP32>(Av, WT, C, aS, aD, es, ed, M, blockIdx.x);
}

// ---------------- aggregation: 8-lane group per node, fp8 gathers ------------
// grp = lane>>3 owns one node; cl = lane&7 covers 16 ch (agg1, uint4) or
// 8 ch (agg2, uint2). Edge loop unrolled x4; no cross-lane reduce in agg1.

__global__ void agg1_kernel(const uint4* __restrict__ h16, const float* __restrict__ es,
                            const float2* __restrict__ ed, const int2* __restrict__ off2,
                            const int* __restrict__ ssrc, const float* __restrict__ b,
                            uint4* __restrict__ outb4, int n) {
  int wv = __builtin_amdgcn_readfirstlane((blockIdx.x * 256 + threadIdx.x) >> 6);
  int lane = threadIdx.x & 63;
  int grp = lane >> 3;         // node slot 0..7
  int cl = lane & 7;           // channel group: channels cl*16 .. cl*16+15
  int w = wv * 8 + grp;
  if (w >= n) return;
  bool hi = cl >= 4;           // head 1 channels (64..127)
  float2 edw = ed[w];
  float edh = hi ? edw.y : edw.x;          // pre-scaled by LOG2E
  const float* esp = es + (hi ? 1 : 0);    // head-offset pointer
  float acc[16] = {};
  float den = 0.f;
  int2 oo = off2[w];
  int e = oo.x, e1 = oo.y;
  for (; e + 4 <= e1; e += 4) {
    int s0 = ssrc[e];
    int s1 = ssrc[e + 1];
    int s2 = ssrc[e + 2];
    int s3 = ssrc[e + 3];
    uint4 g0 = h16[(size_t)s0 * 8 + cl];
    uint4 g1 = h16[(size_t)s1 * 8 + cl];
    uint4 g2 = h16[(size_t)s2 * 8 + cl];
    uint4 g3 = h16[(size_t)s3 * 8 + cl];
    float a0 = exp2f(LRELU(esp[2 * s0] + edh));
    float a1 = exp2f(LRELU(esp[2 * s1] + edh));
    float a2 = exp2f(LRELU(esp[2 * s2] + edh));
    float a3 = exp2f(LRELU(esp[2 * s3] + edh));
    den += (a0 + a1) + (a2 + a3);
    a1_edge(g0, a0, acc);
    a1_edge(g1, a1, acc);
    a1_edge(g2, a2, acc);
    a1_edge(g3, a3, acc);
  }
  for (; e < e1; ++e) {
    int s0 = ssrc[e];
    uint4 g0 = h16[(size_t)s0 * 8 + cl];
    float a0 = exp2f(LRELU(esp[2 * s0] + edh));
    den += a0;
    a1_edge(g0, a0, acc);
  }
  float inv = 1.0f / den;
  float o[16];
#pragma unroll
  for (int k = 0; k < 4; ++k) {
    float4 bb = reinterpret_cast<const float4*>(b)[cl * 4 + k];
    o[k * 4 + 0] = fmaxf(fmaf(acc[k * 4 + 0], inv, bb.x), 0.f);
    o[k * 4 + 1] = fmaxf(fmaf(acc[k * 4 + 1], inv, bb.y), 0.f);
    o[k * 4 + 2] = fmaxf(fmaf(acc[k * 4 + 2], inv, bb.z), 0.f);
    o[k * 4 + 3] = fmaxf(fmaf(acc[k * 4 + 3], inv, bb.w), 0.f);
  }
  uint4 oA, oB;
  oA.x = pack2bf(o[0], o[1]);   oA.y = pack2bf(o[2], o[3]);
  oA.z = pack2bf(o[4], o[5]);   oA.w = pack2bf(o[6], o[7]);
  oB.x = pack2bf(o[8], o[9]);   oB.y = pack2bf(o[10], o[11]);
  oB.z = pack2bf(o[12], o[13]); oB.w = pack2bf(o[14], o[15]);
  outb4[(size_t)w * 16 + cl * 2] = oA;      // bf16 row of 128 for GEMM2
  outb4[(size_t)w * 16 + cl * 2 + 1] = oB;
}

// ---- layer-2 aggregation fused with mean-pool accumulation (atomics) --------

__global__ void agg2_pool_kernel(const uint2* __restrict__ h8,
                                 const float* __restrict__ es,
                                 const float* __restrict__ ed,
                                 const int2* __restrict__ off2,
                                 const int* __restrict__ ssrc,
                                 const float* __restrict__ b,
                                 const int* __restrict__ batch,
                                 float* __restrict__ pooled, int gstride, int n) {
  int t = threadIdx.x;
  int wv = __builtin_amdgcn_readfirstlane((blockIdx.x * 256 + t) >> 6);
  int wave = t >> 6;
  int lane = t & 63;
  int grp = lane >> 3;         // node slot 0..7
  int cl = lane & 7;           // channels cl*8 .. cl*8+7
  int w = wv * 8 + grp;
  bool act = (w < n);
  __shared__ float red[4][64];
  __shared__ int uniS[4];      // >=0 uniform graph; -1 empty; -2 handled
  float* pslice = pooled + (size_t)(blockIdx.x & (PSLICE - 1)) * gstride;
  float acc[8] = {};
  int g = -1;
  if (act) {
    g = batch[w];
    float edw = ed[w];         // pre-scaled by LOG2E
    float den = 0.f;
    int2 oo = off2[w];
    int e = oo.x, e1 = oo.y;
    for (; e + 4 <= e1; e += 4) {
      int s0 = ssrc[e];
      int s1 = ssrc[e + 1];
      int s2 = ssrc[e + 2];
      int s3 = ssrc[e + 3];
      uint2 g0 = h8[(size_t)s0 * 8 + cl];
      uint2 g1 = h8[(size_t)s1 * 8 + cl];
      uint2 g2 = h8[(size_t)s2 * 8 + cl];
      uint2 g3 = h8[(size_t)s3 * 8 + cl];
      float a0 = exp2f(LRELU(es[s0] + edw));
      float a1 = exp2f(LRELU(es[s1] + edw));
      float a2 = exp2f(LRELU(es[s2] + edw));
      float a3 = exp2f(LRELU(es[s3] + edw));
      den += (a0 + a1) + (a2 + a3);
      a2_edge(g0, a0, acc);
      a2_edge(g1, a1, acc);
      a2_edge(g2, a2, acc);
      a2_edge(g3, a3, acc);
    }
    for (; e < e1; ++e) {
      int s0 = ssrc[e];
      uint2 g0 = h8[(size_t)s0 * 8 + cl];
      float a0 = exp2f(LRELU(es[s0] + edw));
      den += a0;
      a2_edge(g0, a0, acc);
    }
    float inv = 1.0f / den;
    float4 b0 = reinterpret_cast<const float4*>(b)[cl * 2];
    float4 b1 = reinterpret_cast<const float4*>(b)[cl * 2 + 1];
    acc[0] = fmaf(acc[0], inv, b0.x);
    acc[1] = fmaf(acc[1], inv, b0.y);
    acc[2] = fmaf(acc[2], inv, b0.z);
    acc[3] = fmaf(acc[3], inv, b0.w);
    acc[4] = fmaf(acc[4], inv, b1.x);
    acc[5] = fmaf(acc[5], inv, b1.y);
    acc[6] = fmaf(acc[6], inv, b1.z);
    acc[7] = fmaf(acc[7], inv, b1.w);
  }
  // wave-level uniformity over the 8 nodes
  int g0lane = __shfl(g, 0);
  bool same = __all(g == g0lane);
  if (same && g0lane >= 0) {
    // butterfly over grp axis (lane bits 3,4,5): every lane ends with the
    // 8-node sum of its channels
#pragma unroll
    for (int m = 8; m <= 32; m <<= 1) {
#pragma unroll
      for (int j = 0; j < 8; ++j) acc[j] += __shfl_xor(acc[j], m);
    }
    if (grp == 0) {
#pragma unroll
      for (int j = 0; j < 8; ++j) red[wave][cl * 8 + j] = acc[j];
    }
    if (lane == 0) uniS[wave] = g0lane;
  } else {
    if (lane == 0) uniS[wave] = same ? -1 : -2;
    if (act && !same) {
      // rare mixed wave: per-node scalar atomics
#pragma unroll
      for (int j = 0; j < 8; ++j)
        atomicAdd(&pslice[(size_t)g * 64 + cl * 8 + j], acc[j]);
    }
  }
  __syncthreads();
  int u0 = uniS[0];
  bool allsame = (u0 >= 0) & (uniS[1] == u0) & (uniS[2] == u0) & (uniS[3] == u0);
  if (allsame) {
    if (t < 64) {
      float s = red[0][t] + red[1][t] + red[2][t] + red[3][t];
      atomicAdd(&pslice[(size_t)u0 * 64 + t], s);
    }
  } else {
    int gw = uniS[wave];
    if (gw >= 0) atomicAdd(&pslice[(size_t)gw * 64 + lane], red[wave][lane]);
  }
}

// ---------------- fused decoder MLP (counts via binary search) ---------------

__device__ __forceinline__ int lowerb(const int* __restrict__ a, int n, int v) {
  int lo = 0, hi = n;
  while (lo < hi) {
    int mid = (lo + hi) >> 1;
    if (a[mid] < v) lo = mid + 1; else hi = mid;
  }
  return lo;
}

__global__ void mlp_kernel(const float* __restrict__ pooled, int gstride,
                           const int* __restrict__ batch, int n,
                           const float* __restrict__ dw1, const float* __restrict__ db1,
                           const float* __restrict__ dw2, const float* __restrict__ db2,
                           float* __restrict__ out) {
  int g = blockIdx.x;
  int c = threadIdx.x;  // 64
  __shared__ float P[64];
  __shared__ float Z[64];
  __shared__ int cntS;
  if (c == 0) cntS = lowerb(batch, n, g + 1) - lowerb(batch, n, g);
  __syncthreads();
  float inv = 1.0f / fmaxf((float)cntS, 1.0f);
  float p = 0.f;
#pragma unroll
  for (int s = 0; s < PSLICE; ++s) p += pooled[(size_t)s * gstride + g * 64 + c];
  P[c] = p * inv;
  __syncthreads();
  float s = db1[c];
#pragma unroll
  for (int k = 0; k < 64; ++k) s = fmaf(P[k], dw1[k * 64 + c], s);
  Z[c] = fmaxf(s, 0.f);
  __syncthreads();
  if (c < 16) {
    float s2 = db2[c];
#pragma unroll
    for (int k = 0; k < 64; ++k) s2 = fmaf(Z[k], dw2[k * 16 + c], s2);
    out[g * 16 + c] = s2;
  }
}

// ---------------- launch ----------------

extern "C" void kernel_launch(void* const* d_in, const int* in_sizes, int n_in,
                              void* d_out, int out_size, void* d_ws, size_t ws_size,
                              hipStream_t stream) {
  const float* x      = (const float*)d_in[0];
  const int*   ei     = (const int*)d_in[1];
  const int*   batch  = (const int*)d_in[2];
  const float* W1     = (const float*)d_in[3];
  const float* a_src1 = (const float*)d_in[4];
  const float* a_dst1 = (const float*)d_in[5];
  const float* b1     = (const float*)d_in[6];
  const float* W2     = (const float*)d_in[7];
  const float* a_src2 = (const float*)d_in[8];
  const float* a_dst2 = (const float*)d_in[9];
  const float* b2     = (const float*)d_in[10];
  const float* dw1    = (const float*)d_in[11];
  const float* db1    = (const float*)d_in[12];
  const float* dw2    = (const float*)d_in[13];
  const float* db2    = (const float*)d_in[14];
  float* out = (float*)d_out;

  const int N = in_sizes[2];
  const int E = in_sizes[1] / 2;
  const int E2 = E + N;
  const int G = out_size / 16;
  const int gstride = G * 64;

  // bucket = 1<<shift nodes; need NB <= 1024 and bsz <= 512
  int shift = 7;
  while ((N >> shift) >= 1024) ++shift;
  const int NB = ((N - 1) >> shift) + 1;

  char* ws = (char*)d_ws;
  size_t o = 0;
  auto alloc = [&](size_t bytes) {
    void* p = ws + o;
    o = (o + bytes + 255) & ~(size_t)255;
    return p;
  };
  // zero region: bcur | pooled slices  (single memset)
  int*      zreg   = (int*)alloc((size_t)(1024 + PSLICE * gstride) * 4);
  int*      bcur   = zreg;
  float*    pooled = (float*)(zreg + 1024);
  int2*     off2   = (int2*)alloc((size_t)N * 8);
  uint32_t* bpack  = (uint32_t*)alloc((size_t)NB * BCAP * 4);
  int*      ssrc   = (int*)alloc((size_t)NB * BCAP * 4);
  float*    es1    = (float*)alloc((size_t)N * 2 * 4);
  float*    ed1    = (float*)alloc((size_t)N * 2 * 4);
  float*    es2    = (float*)alloc((size_t)N * 4);
  float*    ed2    = (float*)alloc((size_t)N * 4);
  uint16_t* wt1b   = (uint16_t*)alloc((size_t)128 * 128 * 2);
  uint16_t* wt2b   = (uint16_t*)alloc((size_t)64 * 128 * 2);
  uint8_t*  hb1    = (uint8_t*)alloc((size_t)N * 128);       // fp8 h1
  uint8_t*  hb2    = (uint8_t*)alloc((size_t)N * 64);        // fp8 h2
  uint32_t* out1b  = (uint32_t*)alloc((size_t)N * 64 * 4);   // bf16 out1 (packed)

  hipMemsetAsync(zreg, 0, (size_t)(1024 + PSLICE * gstride) * 4, stream);

  int gM   = (N + 127) / 128;             // mfma gemm blocks (128 rows each)
  int gW   = (N + 31) / 32;               // agg blocks (32 nodes each)
  int gCH  = (E2 + 4095) / 4096;          // scatter blocks
  int gCVT = (128 * 128 + 64 * 128 + 255) / 256;  // weight-cvt tail blocks

  // K1: edge scatter into fixed-stride buckets + weight convert
  scatter_cvt_kernel<<<gCH + gCVT, 256, 0, stream>>>(ei, bcur, bpack, W1, W2,
                                                     wt1b, wt2b, E, E2, shift,
                                                     NB, gCH);
  // K2: layer-1 GEMM (fp32 A, fused x-convert, fused escore) + bucket finalize
  gemm1_bfinal_kernel<<<gM + NB, 256, 0, stream>>>(x, wt1b, hb1, a_src1, a_dst1,
                                                   es1, ed1, N, bpack, bcur,
                                                   off2, ssrc, shift, gM);
  // K3: layer-1 aggregation (group-per-node, uint4 gathers; bf16 rows out)
  agg1_kernel<<<gW, 256, 0, stream>>>((const uint4*)hb1, es1,
                                      (const float2*)ed1, off2, ssrc, b1,
                                      (uint4*)out1b, N);
  // K4: layer-2 GEMM (bf16 A) + fused escore
  gemm_mfma<64, 1, 0><<<gM, 256, 0, stream>>>((const void*)out1b, wt2b, hb2,
                                              a_src2, a_dst2, es2, ed2, N);
  // K5: layer-2 aggregation fused with pooled accumulation (sliced atomics)
  agg2_pool_kernel<<<gW, 256, 0, stream>>>((const uint2*)hb2, es2, ed2, off2,
                                           ssrc, b2, batch, pooled, gstride, N);
  // K6: decoder MLP (per-graph counts via binary search on sorted batch)
  mlp_kernel<<<G, 64, 0, stream>>>(pooled, gstride, batch, N, dw1, db1, dw2,
                                   db2, out);
}